// Round 2
// baseline (413.241 us; speedup 1.0000x reference)
//
#include <hip/hip_runtime.h>

// Spiking basal ganglia: T=512 sequential LIF steps, B=256 circuits.
// One wave per circuit; lane i owns d1 neurons {2i,2i+1} and d2 neurons {2i,2i+1}.
// STN/GPI populations receive uniform input -> collapse to one scalar each.
// Spike means are exact (0/1 sums / 128) -> ballot+popcount reproduces numpy
// bit-exactly. All elementwise float math mirrors numpy's per-op rounding
// (contract off, reference evaluation order). The K=2 einsum dot is computed
// as an FMA-contracted accumulation loop: fma(x1,w1, round(x0*w0)) — matching
// the reference's dot kernel (R1 post-mortem: separate-rounding version gave
// exactly one spike flip = 1/128 absmax).

__global__ __launch_bounds__(64) void bg_kernel(
    const float* __restrict__ x,      // [T,B,2]
    const float* __restrict__ dopa,   // [T,B]
    const float* __restrict__ Wd1,    // [128,2]
    const float* __restrict__ Wd2,    // [128,2]
    const float* __restrict__ nd1,    // [T,B,128]
    const float* __restrict__ nd2,    // [T,B,128]
    float* __restrict__ out)          // [T,B]
{
#pragma clang fp contract(off)
    constexpr int T = 512, B = 256;
    constexpr int D = 8;  // prefetch depth (register pipeline)

    const int b    = blockIdx.x;
    const int lane = threadIdx.x;

    // Weights for this lane's two neurons in each population:
    // Wd1 row-major [n][i]; neurons n0=2*lane, n1=2*lane+1 -> float4 at 4*lane.
    const float4 w1 = *(const float4*)(Wd1 + 4 * lane);
    const float4 w2 = *(const float4*)(Wd2 + 4 * lane);

    const float* n1base = nd1 + (size_t)b * 128 + 2 * lane;
    const float* n2base = nd2 + (size_t)b * 128 + 2 * lane;
    const float* xbase  = x + (size_t)b * 2;
    const float* dbase  = dopa + b;
    constexpr size_t NSTRIDE = (size_t)B * 128;
    constexpr size_t XSTRIDE = (size_t)B * 2;

    // Register prefetch pipeline, depth D.
    float2 p1[D], p2[D], px[D];
    float  pd[D];
#pragma unroll
    for (int d = 0; d < D; ++d) {
        p1[d] = *(const float2*)(n1base + (size_t)d * NSTRIDE);
        p2[d] = *(const float2*)(n2base + (size_t)d * NSTRIDE);
        px[d] = *(const float2*)(xbase + (size_t)d * XSTRIDE);
        pd[d] = dbase[(size_t)d * B];
    }

    float v1a = 0.0f, v1b = 0.0f;   // d1 voltages (2 per lane)
    float v2a = 0.0f, v2b = 0.0f;   // d2 voltages
    float v_stn = 0.0f, v_gpi = 0.0f;  // wave-uniform scalars

    for (int tt = 0; tt < T; tt += D) {
#pragma unroll
        for (int d = 0; d < D; ++d) {
            const int t = tt + d;
            const float2 n1 = p1[d];
            const float2 n2 = p2[d];
            const float2 xv = px[d];
            const float  dop = pd[d];

            const int tn = t + D;
            if (tn < T) {  // uniform branch; only false in the last outer iter
                p1[d] = *(const float2*)(n1base + (size_t)tn * NSTRIDE);
                p2[d] = *(const float2*)(n2base + (size_t)tn * NSTRIDE);
                px[d] = *(const float2*)(xbase + (size_t)tn * XSTRIDE);
                pd[d] = dbase[(size_t)tn * B];
            }

            // numpy rounding order: each ufunc rounds separately (contract off)
            const float m1 = 1.0f + dop * 0.5f;
            const float m2 = 1.0f - dop * 0.3f;

            // K=2 dot as FMA accumulation loop (matches reference dot kernel):
            // acc = fma(x0,w0,0) = round(x0*w0); acc = fma(x1,w1,acc).
            const float dot1a = __builtin_fmaf(xv.y, w1.y, xv.x * w1.x);
            const float dot1b = __builtin_fmaf(xv.y, w1.w, xv.x * w1.z);
            const float dot2a = __builtin_fmaf(xv.y, w2.y, xv.x * w2.x);
            const float dot2b = __builtin_fmaf(xv.y, w2.w, xv.x * w2.z);

            float Ia = dot1a * m1 + n1.x * 0.1f;
            float Ib = dot1b * m1 + n1.y * 0.1f;
            float Ja = dot2a * m2 + n2.x * 0.1f;
            float Jb = dot2b * m2 + n2.y * 0.1f;

            v1a = 0.8f * v1a + 0.2f * Ia;   // (1-TAU) rounds to exactly 0.2f
            v1b = 0.8f * v1b + 0.2f * Ib;
            v2a = 0.8f * v2a + 0.2f * Ja;
            v2b = 0.8f * v2b + 0.2f * Jb;

            const bool s1a = v1a >= 0.5f, s1b = v1b >= 0.5f;
            const bool s2a = v2a >= 0.5f, s2b = v2b >= 0.5f;
            v1a = s1a ? 0.0f : v1a;
            v1b = s1b ? 0.0f : v1b;
            v2a = s2a ? 0.0f : v2a;
            v2b = s2b ? 0.0f : v2b;

            // exact means: popcount of 0/1 spikes / 128 (power of two)
            const int c1 = __popcll(__ballot(s1a)) + __popcll(__ballot(s1b));
            const int c2 = __popcll(__ballot(s2a)) + __popcll(__ballot(s2b));
            const float mean1 = (float)c1 * 0.0078125f;
            const float mean2 = (float)c2 * 0.0078125f;

            // STN: uniform input -> scalar neuron
            const float I_stn = mean2 * 0.5f;
            v_stn = 0.8f * v_stn + 0.2f * I_stn;
            const float s_stn = (v_stn >= 0.5f) ? 1.0f : 0.0f;
            v_stn = (v_stn >= 0.5f) ? 0.0f : v_stn;

            // GPI: ((tonic + mean1*W_D1_GPI) + s_stn*W_STN_GPI), reference order
            const float I_gpi = (0.4f + mean1 * -0.8f) + s_stn * 0.6f;
            v_gpi = 0.8f * v_gpi + 0.2f * I_gpi;
            const float s_gpi = (v_gpi >= 0.5f) ? 1.0f : 0.0f;
            v_gpi = (v_gpi >= 0.5f) ? 0.0f : v_gpi;

            const float gate = mean1 - s_gpi;
            if (lane == 0) out[(size_t)t * B + b] = gate;
        }
    }
}

extern "C" void kernel_launch(void* const* d_in, const int* in_sizes, int n_in,
                              void* d_out, int out_size, void* d_ws, size_t ws_size,
                              hipStream_t stream) {
    const float* x    = (const float*)d_in[0];
    const float* dopa = (const float*)d_in[1];
    // d_in[2] = rpe — unused by the reference
    const float* Wd1  = (const float*)d_in[3];
    const float* Wd2  = (const float*)d_in[4];
    const float* nd1  = (const float*)d_in[5];
    const float* nd2  = (const float*)d_in[6];
    float* out = (float*)d_out;

    bg_kernel<<<dim3(256), dim3(64), 0, stream>>>(x, dopa, Wd1, Wd2, nd1, nd2, out);
}

// Round 3
// 222.517 us; speedup vs baseline: 1.8571x; 1.8571x over previous
//
#include <hip/hip_runtime.h>

// Spiking basal ganglia: T=512 sequential LIF steps, B=256 circuits.
// One wave per batch; lane i owns d1 neurons {2i,2i+1} and d2 neurons {2i,2i+1}.
// STN/GPI populations get uniform input -> collapse to one scalar each.
// Means are exact popcounts/128 (ballot). Math sequence is bit-identical to
// the R2 passing kernel (contract off, fma-contracted K=2 dots).
//
// R2 post-mortem: VGPR_Count=40 proved the register prefetch pipeline was
// demoted to scratch -> 1420 cyc/step. This version stages noise through LDS
// with __builtin_amdgcn_global_load_lds (double-buffered, 16-step chunks,
// one wave, __syncthreads() as the vmcnt drain) -- the compiler cannot
// un-pipeline DMA-to-LDS.

#define ASYNC_CP(gp, lp, sz)                                                  \
    __builtin_amdgcn_global_load_lds(                                         \
        (const __attribute__((address_space(1))) void*)(gp),                  \
        (__attribute__((address_space(3))) void*)(lp), (sz), 0, 0)

__global__ __launch_bounds__(64) void bg_kernel(
    const float* __restrict__ x,      // [T,B,2]
    const float* __restrict__ dopa,   // [T,B]
    const float* __restrict__ Wd1,    // [128,2]
    const float* __restrict__ Wd2,    // [128,2]
    const float* __restrict__ nd1,    // [T,B,128]
    const float* __restrict__ nd2,    // [T,B,128]
    float* __restrict__ out)          // [T,B]
{
#pragma clang fp contract(off)
    constexpr int T = 512, B = 256;
    constexpr int C = 16;             // steps per LDS chunk
    constexpr int NCH = T / C;        // 32 chunks
    constexpr size_t NSTRIDE = (size_t)B * 128;  // floats per t in noise arrays

    // LDS: per step 1024 B = nd1 row (512 B) + nd2 row (512 B). Double buffer.
    __shared__ alignas(16) char  lds_noise[2][C][1024];   // 32 KB
    __shared__ alignas(16) float lds_x[T * 2];            // 4 KB
    __shared__ alignas(16) float lds_d[T];                // 2 KB

    const int b    = blockIdx.x;
    const int lane = threadIdx.x;

    const float4 w1 = *(const float4*)(Wd1 + 4 * lane);
    const float4 w2 = *(const float4*)(Wd2 + 4 * lane);

    // Per-lane global source for the noise DMA: lanes 0-31 carry this step's
    // nd1 row (16 B each), lanes 32-63 the nd2 row. HW deposits each lane at
    // ldsbase + lane*16 -> [nd1 row | nd2 row] per step.
    const float* nbase = (lane < 32)
        ? (nd1 + (size_t)b * 128 + (size_t)lane * 4)
        : (nd2 + (size_t)b * 128 + (size_t)(lane - 32) * 4);

    // ---- prologue: stage x and dopa for this batch (whole T) ----
#pragma unroll
    for (int i = 0; i < 16; ++i) {            // 1024 floats of x
        const int e = i * 64 + lane;          // element in [T][2] for batch b
        const int t = e >> 1, c = e & 1;
        ASYNC_CP(x + (size_t)t * (B * 2) + b * 2 + c, &lds_x[i * 64], 4);
    }
#pragma unroll
    for (int i = 0; i < 8; ++i) {             // 512 floats of dopa
        const int e = i * 64 + lane;
        ASYNC_CP(dopa + (size_t)e * B + b, &lds_d[i * 64], 4);
    }

    // ---- issue noise chunks 0 and 1 ----
#pragma unroll
    for (int s = 0; s < C; ++s)
        ASYNC_CP(nbase + (size_t)s * NSTRIDE, &lds_noise[0][s][0], 16);
#pragma unroll
    for (int s = 0; s < C; ++s)
        ASYNC_CP(nbase + (size_t)(C + s) * NSTRIDE, &lds_noise[1][s][0], 16);

    __syncthreads();   // drain vmcnt: x, dopa, chunks 0 & 1 resident

    float v1a = 0.0f, v1b = 0.0f;
    float v2a = 0.0f, v2b = 0.0f;
    float v_stn = 0.0f, v_gpi = 0.0f;

    for (int k = 0; k < NCH; ++k) {
        const char* buf = &lds_noise[k & 1][0][0];

#pragma unroll
        for (int s = 0; s < C; ++s) {
            const int t = k * C + s;
            const float2 n1 = *(const float2*)(buf + s * 1024 + lane * 8);
            const float2 n2 = *(const float2*)(buf + s * 1024 + 512 + lane * 8);
            const float2 xv = *(const float2*)(&lds_x[t * 2]);   // uniform
            const float  dop = lds_d[t];                          // uniform

            // ---- bit-identical math to the R2 passing kernel ----
            const float m1 = 1.0f + dop * 0.5f;
            const float m2 = 1.0f - dop * 0.3f;

            const float dot1a = __builtin_fmaf(xv.y, w1.y, xv.x * w1.x);
            const float dot1b = __builtin_fmaf(xv.y, w1.w, xv.x * w1.z);
            const float dot2a = __builtin_fmaf(xv.y, w2.y, xv.x * w2.x);
            const float dot2b = __builtin_fmaf(xv.y, w2.w, xv.x * w2.z);

            float Ia = dot1a * m1 + n1.x * 0.1f;
            float Ib = dot1b * m1 + n1.y * 0.1f;
            float Ja = dot2a * m2 + n2.x * 0.1f;
            float Jb = dot2b * m2 + n2.y * 0.1f;

            v1a = 0.8f * v1a + 0.2f * Ia;
            v1b = 0.8f * v1b + 0.2f * Ib;
            v2a = 0.8f * v2a + 0.2f * Ja;
            v2b = 0.8f * v2b + 0.2f * Jb;

            const bool s1a = v1a >= 0.5f, s1b = v1b >= 0.5f;
            const bool s2a = v2a >= 0.5f, s2b = v2b >= 0.5f;
            v1a = s1a ? 0.0f : v1a;
            v1b = s1b ? 0.0f : v1b;
            v2a = s2a ? 0.0f : v2a;
            v2b = s2b ? 0.0f : v2b;

            const int c1 = __popcll(__ballot(s1a)) + __popcll(__ballot(s1b));
            const int c2 = __popcll(__ballot(s2a)) + __popcll(__ballot(s2b));
            const float mean1 = (float)c1 * 0.0078125f;
            const float mean2 = (float)c2 * 0.0078125f;

            const float I_stn = mean2 * 0.5f;
            v_stn = 0.8f * v_stn + 0.2f * I_stn;
            const float s_stn = (v_stn >= 0.5f) ? 1.0f : 0.0f;
            v_stn = (v_stn >= 0.5f) ? 0.0f : v_stn;

            const float I_gpi = (0.4f + mean1 * -0.8f) + s_stn * 0.6f;
            v_gpi = 0.8f * v_gpi + 0.2f * I_gpi;
            const float s_gpi = (v_gpi >= 0.5f) ? 1.0f : 0.0f;
            v_gpi = (v_gpi >= 0.5f) ? 0.0f : v_gpi;

            const float gate = mean1 - s_gpi;
            if (lane == 0) out[(size_t)t * B + b] = gate;
        }

        // Retire this chunk's LDS reads + land chunk k+1, THEN reuse buffer.
        __syncthreads();

        const int kn = k + 2;
        if (kn < NCH) {
            char* nbuf = &lds_noise[k & 1][0][0];
#pragma unroll
            for (int s = 0; s < C; ++s)
                ASYNC_CP(nbase + (size_t)(kn * C + s) * NSTRIDE,
                         nbuf + s * 1024, 16);
        }
    }
}

extern "C" void kernel_launch(void* const* d_in, const int* in_sizes, int n_in,
                              void* d_out, int out_size, void* d_ws, size_t ws_size,
                              hipStream_t stream) {
    const float* x    = (const float*)d_in[0];
    const float* dopa = (const float*)d_in[1];
    // d_in[2] = rpe — unused by the reference
    const float* Wd1  = (const float*)d_in[3];
    const float* Wd2  = (const float*)d_in[4];
    const float* nd1  = (const float*)d_in[5];
    const float* nd2  = (const float*)d_in[6];
    float* out = (float*)d_out;

    bg_kernel<<<dim3(256), dim3(64), 0, stream>>>(x, dopa, Wd1, Wd2, nd1, nd2, out);
}